// Round 3
// baseline (455.742 us; speedup 1.0000x reference)
//
#include <hip/hip_runtime.h>
#include <math.h>

#define BB 64
#define SS 2048
#define DD 512
#define CH 32               // chunks per batch row (was 16) -> 2048 blocks, 8/CU
#define ROWS (SS/CH)        // 64 rows per chunk
#define WROWS (ROWS/4)      // 16 rows per wave
#define RPI 2               // rows per wave-iteration (keeps VGPR low for occupancy)
#define ITERS (WROWS/RPI)   // 8 iterations per wave

// ---------------- kernel 1: w[b,d] = (concat(c1,q)[b,:] . W_d2d[d,:] + b_d[d]) * W_1d[d]
__global__ __launch_bounds__(128) void k_w(
    const float* __restrict__ c1, const float* __restrict__ q,
    const float* __restrict__ Wd, const float* __restrict__ bd,
    const float* __restrict__ W1, float* __restrict__ w)
{
    __shared__ float conc[2*DD];
    const int b = blockIdx.y;
    const int t = threadIdx.x;
    for (int i = t; i < DD; i += 128) {
        conc[i]      = c1[b*DD + i];
        conc[DD + i] = q[b*DD + i];
    }
    __syncthreads();
    const int d = blockIdx.x * 128 + t;
    const float4* Wr = (const float4*)(Wd + (size_t)d * (2*DD));
    const float4* cc = (const float4*)conc;
    float acc = 0.f;
    #pragma unroll 8
    for (int k = 0; k < (2*DD)/4; ++k) {
        float4 a = Wr[k];
        float4 c = cc[k];
        acc += a.x*c.x + a.y*c.y + a.z*c.z + a.w*c.w;
    }
    w[b*DD + d] = (acc + bd[d]) * W1[d];
}

// ---------------- kernel 2: online-softmax partial over a chunk of 64 rows
// OCCUPANCY PROBE: 2048 blocks (8/CU vs previous grid-limited 4/CU), RPI=2,
// no explicit prefetch registers (rely on unroll pipelining) to keep VGPR
// low enough for >=6 waves/SIMD.
__global__ __launch_bounds__(256, 6) void k_pass(
    const float* __restrict__ cw, const float* __restrict__ w,
    float* __restrict__ pm, float* __restrict__ pl, float* __restrict__ pacc)
{
    const int blk  = blockIdx.x;
    const int b    = blk >> 5;        // /CH
    const int ch   = blk & (CH - 1);
    const int tid  = threadIdx.x;
    const int wave = tid >> 6;
    const int lane = tid & 63;

    // per-lane slice of w: d = 4*lane .. +3  and  256 + 4*lane .. +3
    const float4* wb = (const float4*)(w + b*DD);
    const float4 w0 = wb[lane];
    const float4 w1 = wb[64 + lane];

    // wave's contiguous 16-row strip
    const float* rb = cw + ((size_t)b*SS + (size_t)ch*ROWS + (size_t)wave*WROWS) * DD;

    float m = -INFINITY, l = 0.f;
    float4 a0 = make_float4(0,0,0,0), a1 = make_float4(0,0,0,0);

    #pragma unroll
    for (int i = 0; i < ITERS; ++i) {
        float4 c0[RPI], c1v[RPI];
        #pragma unroll
        for (int r = 0; r < RPI; ++r) {
            const float4* p = (const float4*)(rb + (size_t)(i*RPI + r) * DD);
            c0[r]  = p[lane];
            c1v[r] = p[64 + lane];
        }

        float d_[RPI];
        #pragma unroll
        for (int r = 0; r < RPI; ++r) {
            d_[r] = c0[r].x*w0.x + c0[r].y*w0.y + c0[r].z*w0.z + c0[r].w*w0.w
                  + c1v[r].x*w1.x + c1v[r].y*w1.y + c1v[r].z*w1.z + c1v[r].w*w1.w;
        }
        // 2 independent butterflies pipeline through the 6 steps
        #pragma unroll
        for (int off = 32; off; off >>= 1) {
            #pragma unroll
            for (int r = 0; r < RPI; ++r) d_[r] += __shfl_xor(d_[r], off, 64);
        }

        // batched online-softmax update (one rescale per 2 rows)
        const float mn = fmaxf(fmaxf(d_[0], d_[1]), m);
        const float alpha = __expf(m - mn);   // first iter: expf(-inf) = 0
        m = mn;
        const float p0 = __expf(d_[0] - m);
        const float p1 = __expf(d_[1] - m);
        l = l*alpha + p0 + p1;
        a0.x = a0.x*alpha + p0*c0[0].x  + p1*c0[1].x;
        a0.y = a0.y*alpha + p0*c0[0].y  + p1*c0[1].y;
        a0.z = a0.z*alpha + p0*c0[0].z  + p1*c0[1].z;
        a0.w = a0.w*alpha + p0*c0[0].w  + p1*c0[1].w;
        a1.x = a1.x*alpha + p0*c1v[0].x + p1*c1v[1].x;
        a1.y = a1.y*alpha + p0*c1v[0].y + p1*c1v[1].y;
        a1.z = a1.z*alpha + p0*c1v[0].z + p1*c1v[1].z;
        a1.w = a1.w*alpha + p0*c1v[0].w + p1*c1v[1].w;
    }

    // combine 4 waves within the block
    __shared__ float lm[4], ll[4];
    __shared__ float lacc[4][DD];
    if (lane == 0) lm[wave] = m;
    __syncthreads();
    const float M = fmaxf(fmaxf(lm[0], lm[1]), fmaxf(lm[2], lm[3]));
    const float beta = __expf(m - M);
    float4* lw = (float4*)lacc[wave];
    lw[lane]      = make_float4(a0.x*beta, a0.y*beta, a0.z*beta, a0.w*beta);
    lw[64 + lane] = make_float4(a1.x*beta, a1.y*beta, a1.z*beta, a1.w*beta);
    if (lane == 0) ll[wave] = l * beta;
    __syncthreads();
    const float s0 = lacc[0][tid]     + lacc[1][tid]     + lacc[2][tid]     + lacc[3][tid];
    const float s1 = lacc[0][tid+256] + lacc[1][tid+256] + lacc[2][tid+256] + lacc[3][tid+256];
    pacc[(size_t)blk*DD + tid]       = s0;
    pacc[(size_t)blk*DD + tid + 256] = s1;
    if (tid == 0) {
        pm[blk] = M;
        pl[blk] = ll[0] + ll[1] + ll[2] + ll[3];
    }
}

// ---------------- kernel 3: merge 32 chunk-partials per batch (float2-vectorized)
__global__ __launch_bounds__(256) void k_comb(
    const float* __restrict__ pm, const float* __restrict__ pl,
    const float* __restrict__ pacc, float* __restrict__ out)
{
    const int b = blockIdx.x;
    const int tid = threadIdx.x;
    float M = -INFINITY;
    #pragma unroll
    for (int p = 0; p < CH; ++p) M = fmaxf(M, pm[b*CH + p]);
    float L = 0.f;
    float sx = 0.f, sy = 0.f;
    #pragma unroll
    for (int p = 0; p < CH; ++p) {
        const float sc = __expf(pm[b*CH + p] - M);
        L += pl[b*CH + p] * sc;
        const float2 v = ((const float2*)(pacc + (size_t)(b*CH + p)*DD))[tid];
        sx += sc * v.x;
        sy += sc * v.y;
    }
    const float inv = 1.f / L;
    ((float2*)(out + b*DD))[tid] = make_float2(sx*inv, sy*inv);
}

extern "C" void kernel_launch(void* const* d_in, const int* in_sizes, int n_in,
                              void* d_out, int out_size, void* d_ws, size_t ws_size,
                              hipStream_t stream)
{
    const float* c1 = (const float*)d_in[0];   // c_i_1 [B,D]
    const float* q  = (const float*)d_in[1];   // q     [B,D]
    const float* cw = (const float*)d_in[2];   // cw_s  [B,S,D]
    const float* Wd = (const float*)d_in[3];   // W_d2d [D,2D]
    const float* bd = (const float*)d_in[4];   // b_d   [D]
    const float* W1 = (const float*)d_in[5];   // W_1d  [1,D]
    // d_in[6] = b_1: constant logit shift -> cancels in softmax, unused.

    float* out  = (float*)d_out;
    float* ws   = (float*)d_ws;
    float* w    = ws;                    // B*D          = 32768 floats
    float* pm   = w  + BB*DD;            // B*CH         = 2048
    float* pl   = pm + BB*CH;            // B*CH         = 2048
    float* pacc = pl + BB*CH;            // B*CH*D       = 1048576 floats (4 MB)

    k_w   <<<dim3(DD/128, BB), 128, 0, stream>>>(c1, q, Wd, bd, W1, w);
    k_pass<<<BB*CH,            256, 0, stream>>>(cw, w, pm, pl, pacc);
    k_comb<<<BB,               256, 0, stream>>>(pm, pl, pacc, out);
}